// Round 13
// baseline (865.403 us; speedup 1.0000x reference)
//
#include <hip/hip_runtime.h>
#include <hip/hip_bf16.h>

#define N_NODES 98304
#define N_GRAPHS 2048
#define N_EDGES 393216
#define EMB 64
#define HID 256
#define N_LAYERS_ 6

typedef __attribute__((ext_vector_type(8))) short short8v;
typedef __attribute__((ext_vector_type(4))) float f32x4;
#define MFMA16(a, b, c) __builtin_amdgcn_mfma_f32_16x16x32_bf16(a, b, c, 0, 0, 0)

__device__ __forceinline__ unsigned short f2bf(float x) {
    unsigned int u = __float_as_uint(x);
    u = (u + 0x7fffu + ((u >> 16) & 1u)) >> 16;
    return (unsigned short)u;
}
__device__ __forceinline__ float bf2f(unsigned short h) {
    return __uint_as_float(((unsigned int)h) << 16);
}
// pack 2 floats -> 2 bf16 (RNE): low16 = a, high16 = b
__device__ __forceinline__ unsigned int cvtpk(float a, float b) {
    unsigned int r;
    asm("v_cvt_pk_bf16_f32 %0, %1, %2" : "=v"(r) : "v"(a), "v"(b));
    return r;
}
// swizzled index (ushort units): XOR 16B-slot id with low row bits (bijective)
__device__ __forceinline__ int swz(int row, int col, int rowc) {
    return (row * rowc + col) ^ ((row & ((rowc >> 3) - 1)) << 3);
}

// ---------------- histogram of edge rows ----------------
__global__ __launch_bounds__(256) void zero_cnt_kernel(int* __restrict__ cnt) {
    int i = blockIdx.x * 256 + threadIdx.x;
    if (i < N_NODES) cnt[i] = 0;
}
__global__ __launch_bounds__(256) void hist_kernel(const int* __restrict__ row,
                                                   int* __restrict__ cnt) {
    int i = blockIdx.x * 256 + threadIdx.x;
    if (i < N_EDGES) atomicAdd(&cnt[row[i]], 1);
}

// ---------------- weight prep: fp32 [L][K][N] -> hi/lo bf16 MFMA B-frags ----
__global__ __launch_bounds__(64) void prep_frag_kernel(
    const float* __restrict__ W, unsigned short* __restrict__ oh,
    unsigned short* __restrict__ ol, int K, int N)
{
    const int NF = N >> 4, KS = K >> 5;
    const int fpl = NF * KS;
    const int layer = blockIdx.x / fpl;
    const int fid = blockIdx.x % fpl;
    const int nf = fid / KS, ks = fid % KS;
    const int lane = threadIdx.x;
    const float* Wl = W + (size_t)layer * K * N;
    const int n = nf * 16 + (lane & 15);
    const int kb = ks * 32 + (lane >> 4) * 8;
    short8v vh, vl;
    #pragma unroll
    for (int j = 0; j < 8; j++) {
        float wv = Wl[(size_t)(kb + j) * N + n];
        unsigned short hi = f2bf(wv);
        vh[j] = (short)hi;
        vl[j] = (short)f2bf(wv - bf2f(hi));
    }
    size_t o = (size_t)layer * K * N + ((size_t)(nf * KS + ks) * 64 + lane) * 8;
    *reinterpret_cast<short8v*>(oh + o) = vh;
    *reinterpret_cast<short8v*>(ol + o) = vl;
}

// ---------------- G = per-head (Wp @ Wv) fold + d vector --------------------
__global__ __launch_bounds__(256) void gbuild_kernel(
    const float* __restrict__ Wp, const float* __restrict__ bp,
    const float* __restrict__ W_in, const float* __restrict__ b_in,
    float* __restrict__ Gm, float* __restrict__ Gd)
{
    const int idx = blockIdx.x * 256 + threadIdx.x;
    const int q = idx >> 8, p = idx & 255;
    float s = 0.f;
    if ((q >> 6) == (p >> 6)) {
        const float* wr = Wp + (q & 63) * 256;
        for (int j = 0; j < 256; j++) s += wr[j] * W_in[j * 768 + 512 + p];
    }
    Gm[q * 256 + p] = s;
    if (blockIdx.x == 0) {
        const int pp = threadIdx.x;
        float dsum = b_in[512 + pp];
        for (int j = 0; j < 256; j++) dsum += bp[j] * W_in[j * 768 + 512 + pp];
        Gd[pp] = dsum;
    }
}

// ---------------- embed via split MFMA: h = x @ W_embed + b -----------------
__global__ __launch_bounds__(256) void embed_mfma_kernel(
    const float* __restrict__ x,
    const unsigned short* __restrict__ Weh, const unsigned short* __restrict__ Wel,
    const float* __restrict__ b, float* __restrict__ h)
{
    __shared__ __attribute__((aligned(16))) unsigned short xh[32 * 128];
    __shared__ __attribute__((aligned(16))) unsigned short xl[32 * 128];
    const int tid = threadIdx.x;
    const int lane = tid & 63, w = tid >> 6;
    const int lm = lane & 15, lq = lane >> 4;
    const int base = blockIdx.x * 32;
    {
        int row = tid >> 3, c0 = (tid & 7) * 16;
        const float4* p = reinterpret_cast<const float4*>(x + (size_t)(base + row) * 128 + c0);
        #pragma unroll
        for (int g = 0; g < 4; g++) {
            float4 u = p[g];
            unsigned int p01 = cvtpk(u.x, u.y);
            unsigned int p23 = cvtpk(u.z, u.w);
            float h0 = __uint_as_float(p01 << 16), h1 = __uint_as_float(p01 & 0xffff0000u);
            float h2 = __uint_as_float(p23 << 16), h3 = __uint_as_float(p23 & 0xffff0000u);
            unsigned int q01 = cvtpk(u.x - h0, u.y - h1);
            unsigned int q23 = cvtpk(u.z - h2, u.w - h3);
            int idx = swz(row, c0 + g * 4, 128);
            *reinterpret_cast<uint2*>(&xh[idx]) = make_uint2(p01, p23);
            *reinterpret_cast<uint2*>(&xl[idx]) = make_uint2(q01, q23);
        }
    }
    __syncthreads();
    f32x4 acc0, acc1;
    {
        float bv = b[w * 16 + lm];
        acc0 = f32x4{bv, bv, bv, bv};
        acc1 = acc0;
    }
    #pragma unroll
    for (int ks = 0; ks < 4; ks++) {
        short8v a0h = *reinterpret_cast<const short8v*>(&xh[swz(lm, ks * 32 + lq * 8, 128)]);
        short8v a0l = *reinterpret_cast<const short8v*>(&xl[swz(lm, ks * 32 + lq * 8, 128)]);
        short8v a1h = *reinterpret_cast<const short8v*>(&xh[swz(16 + lm, ks * 32 + lq * 8, 128)]);
        short8v a1l = *reinterpret_cast<const short8v*>(&xl[swz(16 + lm, ks * 32 + lq * 8, 128)]);
        size_t bi = ((size_t)(w * 4 + ks) * 64 + lane) * 8;
        short8v bh = *reinterpret_cast<const short8v*>(Weh + bi);
        short8v bl = *reinterpret_cast<const short8v*>(Wel + bi);
        acc0 = MFMA16(a0h, bh, acc0); acc0 = MFMA16(a0l, bh, acc0); acc0 = MFMA16(a0h, bl, acc0);
        acc1 = MFMA16(a1h, bh, acc1); acc1 = MFMA16(a1l, bh, acc1); acc1 = MFMA16(a1h, bl, acc1);
    }
    #pragma unroll
    for (int r = 0; r < 4; r++) {
        h[(size_t)(base + lq * 4 + r) * 64 + w * 16 + lm] = acc0[r];
        h[(size_t)(base + 16 + lq * 4 + r) * 64 + w * 16 + lm] = acc1[r];
    }
}

// ---- helper: split-convert 4 row-consecutive values, store hi/lo to LDS ----
__device__ __forceinline__ void store_quad(
    unsigned short* __restrict__ oh, unsigned short* __restrict__ ol,
    float v0, float v1, float v2, float v3,
    int row0, int col, int rowc)
{
    unsigned int p01 = cvtpk(v0, v1);
    unsigned int p23 = cvtpk(v2, v3);
    float h0 = __uint_as_float(p01 << 16), h1 = __uint_as_float(p01 & 0xffff0000u);
    float h2 = __uint_as_float(p23 << 16), h3 = __uint_as_float(p23 & 0xffff0000u);
    unsigned int q01 = cvtpk(v0 - h0, v1 - h1);
    unsigned int q23 = cvtpk(v2 - h2, v3 - h3);
    oh[swz(row0 + 0, col, rowc)] = (unsigned short)p01;
    oh[swz(row0 + 1, col, rowc)] = (unsigned short)(p01 >> 16);
    oh[swz(row0 + 2, col, rowc)] = (unsigned short)p23;
    oh[swz(row0 + 3, col, rowc)] = (unsigned short)(p23 >> 16);
    ol[swz(row0 + 0, col, rowc)] = (unsigned short)q01;
    ol[swz(row0 + 1, col, rowc)] = (unsigned short)(q01 >> 16);
    ol[swz(row0 + 2, col, rowc)] = (unsigned short)q23;
    ol[swz(row0 + 3, col, rowc)] = (unsigned short)(q23 >> 16);
}

// ---------------- fused MLP layer, v10: N=2 blocking, 256-col chunks --------
// 32 nodes/block, 8 waves, LDS 64KB -> 2 blocks/CU. Each wave computes 2
// col-frags per chunk -> stage-B m1 reads halve. 6 barriers; one wide
// overlap phase runs C(chunk0) and B-compute(chunk1) barrier-free.
__global__ __launch_bounds__(512, 4) void layer_mfma_kernel(
    float* __restrict__ h, const int* __restrict__ cnt,
    const unsigned short* __restrict__ W1h, const unsigned short* __restrict__ W1l,
    const float* __restrict__ b1,
    const unsigned short* __restrict__ W2h, const unsigned short* __restrict__ W2l,
    const float* __restrict__ b2,
    const unsigned short* __restrict__ W3h, const unsigned short* __restrict__ W3l,
    const float* __restrict__ b3)
{
    __shared__ __attribute__((aligned(16))) unsigned short m1h_[8192];  // 16KB [32x256]
    __shared__ __attribute__((aligned(16))) unsigned short m1l_[8192];  // 16KB
    __shared__ __attribute__((aligned(16))) unsigned short m2_[16384];  // 32KB: hi+lo [32x256]
    unsigned short* m2h_ = m2_;
    unsigned short* m2l_ = m2_ + 8192;
    unsigned short* hsh = m2_;          // 32x64 (dead after stage A)
    unsigned short* hsl = m2_ + 2048;
    float* scr = reinterpret_cast<float*>(m1h_);   // 2048 f32 = 8KB

    const int tid = threadIdx.x;
    const int lane = tid & 63, w = tid >> 6;
    const int lm = lane & 15, lq = lane >> 4;
    const int base = blockIdx.x * 32;

    // issue stage-0 global load first (longest chain)
    int s0row = tid >> 4, s0c = (tid & 15) * 4;
    const float4 u0 = *reinterpret_cast<const float4*>(h + (size_t)(base + s0row) * 64 + s0c);

    // stage-A weight preload: frag indices 4w + (2f+ks)
    const unsigned short* pAh = W1h + ((size_t)(4 * w) * 64 + lane) * 8;
    const unsigned short* pAl = W1l + ((size_t)(4 * w) * 64 + lane) * 8;
    short8v awh[4], awl[4];
    #pragma unroll
    for (int i = 0; i < 4; i++) {
        awh[i] = *reinterpret_cast<const short8v*>(pAh + (size_t)i * 512);
        awl[i] = *reinterpret_cast<const short8v*>(pAl + (size_t)i * 512);
    }

    {   // stage 0: h tile (fp32 32x64) -> hi/lo bf16 planes
        unsigned int p01 = cvtpk(u0.x, u0.y);
        unsigned int p23 = cvtpk(u0.z, u0.w);
        float h0 = __uint_as_float(p01 << 16), h1 = __uint_as_float(p01 & 0xffff0000u);
        float h2 = __uint_as_float(p23 << 16), h3 = __uint_as_float(p23 & 0xffff0000u);
        unsigned int q01 = cvtpk(u0.x - h0, u0.y - h1);
        unsigned int q23 = cvtpk(u0.z - h2, u0.w - h3);
        int idx = swz(s0row, s0c, 64);
        *reinterpret_cast<uint2*>(&hsh[idx]) = make_uint2(p01, p23);
        *reinterpret_cast<uint2*>(&hsl[idx]) = make_uint2(q01, q23);
    }
    __syncthreads();                                            // bar 1

    // ---- stage A: m1 = relu(hs @ W1 + b1)  [32x256]; wave w -> frags {2w,2w+1}
    {
        f32x4 acc[2][2];   // [f][m]
        #pragma unroll
        for (int f = 0; f < 2; f++) {
            float bv = b1[(2 * w + f) * 16 + lm];
            acc[f][0] = f32x4{bv, bv, bv, bv};
            acc[f][1] = acc[f][0];
        }
        __builtin_amdgcn_s_setprio(1);
        #pragma unroll
        for (int ks = 0; ks < 2; ks++) {
            short8v ah0 = *reinterpret_cast<const short8v*>(&hsh[swz(lm, ks * 32 + lq * 8, 64)]);
            short8v al0 = *reinterpret_cast<const short8v*>(&hsl[swz(lm, ks * 32 + lq * 8, 64)]);
            short8v ah1 = *reinterpret_cast<const short8v*>(&hsh[swz(16 + lm, ks * 32 + lq * 8, 64)]);
            short8v al1 = *reinterpret_cast<const short8v*>(&hsl[swz(16 + lm, ks * 32 + lq * 8, 64)]);
            #pragma unroll
            for (int f = 0; f < 2; f++) {
                short8v bh = awh[2 * f + ks];
                short8v bl = awl[2 * f + ks];
                acc[f][0] = MFMA16(ah0, bh, acc[f][0]);
                acc[f][0] = MFMA16(al0, bh, acc[f][0]);
                acc[f][0] = MFMA16(ah0, bl, acc[f][0]);
                acc[f][1] = MFMA16(ah1, bh, acc[f][1]);
                acc[f][1] = MFMA16(al1, bh, acc[f][1]);
                acc[f][1] = MFMA16(ah1, bl, acc[f][1]);
            }
        }
        __builtin_amdgcn_s_setprio(0);
        #pragma unroll
        for (int f = 0; f < 2; f++)
            #pragma unroll
            for (int m = 0; m < 2; m++)
                store_quad(m1h_, m1l_,
                           fmaxf(acc[f][m][0], 0.f), fmaxf(acc[f][m][1], 0.f),
                           fmaxf(acc[f][m][2], 0.f), fmaxf(acc[f][m][3], 0.f),
                           m * 16 + lq * 4, (2 * w + f) * 16 + lm, 256);
    }
    __syncthreads();                                            // bar 2
    // all hs reads done + m1 visible; m2 region (incl. hs) free for B0 stores

    const int nfc = w & 3, kq = w >> 2;
    f32x4 dacc[2];
    if (kq == 0) {
        float bv = b3[nfc * 16 + lm];
        dacc[0] = f32x4{bv, bv, bv, bv};
    } else {
        dacc[0] = f32x4{0.f, 0.f, 0.f, 0.f};
    }
    dacc[1] = dacc[0];

    f32x4 accB[2][2];   // [f][m], reused for both chunks

    // ================= chunk 0 =================
    {   // B0 compute: cols frags {2w, 2w+1} of chunk 0 (global cols (2w+f)*16)
        const int nfg0 = 2 * w;
        #pragma unroll
        for (int f = 0; f < 2; f++) {
            float bv = b2[(nfg0 + f) * 16 + lm];
            accB[f][0] = f32x4{bv, bv, bv, bv};
            accB[f][1] = accB[f][0];
        }
        __builtin_amdgcn_s_setprio(1);
        #pragma unroll
        for (int ks = 0; ks < 8; ks++) {
            short8v ah0 = *reinterpret_cast<const short8v*>(&m1h_[swz(lm, ks * 32 + lq * 8, 256)]);
            short8v al0 = *reinterpret_cast<const short8v*>(&m1l_[swz(lm, ks * 32 + lq * 8, 256)]);
            short8v ah1 = *reinterpret_cast<const short8v*>(&m1h_[swz(16 + lm, ks * 32 + lq * 8, 256)]);
            short8v al1 = *reinterpret_cast<const short8v*>(&m1l_[swz(16 + lm, ks * 32 + lq * 8, 256)]);
            #pragma unroll
            for (int f = 0; f < 2; f++) {
                size_t bi = ((size_t)((nfg0 + f) * 8 + ks) * 64 + lane) * 8;
                short8v bh = *reinterpret_cast<const short8v*>(W2h + bi);
                short8v bl = *reinterpret_cast<const short8v*>(W2l + bi);
                accB[f][0] = MFMA16(ah0, bh, accB[f][0]);
                accB[f][0] = MFMA16(al0, bh, accB[f][0]);
                accB[f][0] = MFMA16(ah0, bl, accB[f][0]);
                accB[f][1] = MFMA16(ah1, bh, accB[f][1]);
                accB[f][1] = MFMA16(al1, bh, accB[f][1]);
                accB[f][1] = MFMA16(ah1, bl, accB[f][1]);
            }
        }
        __builtin_amdgcn_s_setprio(0);
        #pragma unroll
        for (int f = 0; f < 2; f++)
            #pragma unroll
            for (int m = 0; m < 2; m++)
                store_quad(m2h_, m2l_,
                           fmaxf(accB[f][m][0], 0.f), fmaxf(accB[f][m][1], 0.f),
                           fmaxf(accB[f][m][2], 0.f), fmaxf(accB[f][m][3], 0.f),
                           m * 16 + lq * 4, (2 * w + f) * 16 + lm, 256);
    }
    __syncthreads();                                            // bar 3

    // ======= overlap phase: C(chunk 0) + B-compute(chunk 1), barrier-free ====
    {   // C0: dacc += m2c0[:, kq quarter] @ W3[k 0..255]
        __builtin_amdgcn_s_setprio(1);
        #pragma unroll
        for (int kl = 0; kl < 4; kl++) {
            int ksl = kq * 4 + kl;
            short8v ah0 = *reinterpret_cast<const short8v*>(&m2h_[swz(lm, ksl * 32 + lq * 8, 256)]);
            short8v al0 = *reinterpret_cast<const short8v*>(&m2l_[swz(lm, ksl * 32 + lq * 8, 256)]);
            short8v ah1 = *reinterpret_cast<const short8v*>(&m2h_[swz(16 + lm, ksl * 32 + lq * 8, 256)]);
            short8v al1 = *reinterpret_cast<const short8v*>(&m2l_[swz(16 + lm, ksl * 32 + lq * 8, 256)]);
            size_t bi = ((size_t)(nfc * 16 + ksl) * 64 + lane) * 8;
            short8v ch = *reinterpret_cast<const short8v*>(W3h + bi);
            short8v cl = *reinterpret_cast<const short8v*>(W3l + bi);
            dacc[0] = MFMA16(ah0, ch, dacc[0]);
            dacc[0] = MFMA16(al0, ch, dacc[0]);
            dacc[0] = MFMA16(ah0, cl, dacc[0]);
            dacc[1] = MFMA16(ah1, ch, dacc[1]);
            dacc[1] = MFMA16(al1, ch, dacc[1]);
            dacc[1] = MFMA16(ah1, cl, dacc[1]);
        }
        __builtin_amdgcn_s_setprio(0);
    }
    {   // B1 compute (reads m1 only; stores deferred past bar 4)
        const int nfg0 = 16 + 2 * w;
        #pragma unroll
        for (int f = 0; f < 2; f++) {
            float bv = b2[(nfg0 + f) * 16 + lm];
            accB[f][0] = f32x4{bv, bv, bv, bv};
            accB[f][1] = accB[f][0];
        }
        __builtin_amdgcn_s_setprio(1);
        #pragma unroll
        for (int ks = 0; ks < 8; ks++) {
            short8v ah0 = *reinterpret_cast<const short8v*>(&m1h_[swz(lm, ks * 32 + lq * 8, 256)]);
            short8v al0 = *reinterpret_cast<const short8v*>(&m1l_[swz(lm, ks * 32 + lq * 8, 256)]);
            short8v ah1 = *reinterpret_cast<const short8v*>(&m1h_[swz(16 + lm, ks * 32 + lq * 8, 256)]);
            short8v al1 = *reinterpret_cast<const short8v*>(&m1l_[swz(16 + lm, ks * 32 + lq * 8, 256)]);
            #pragma unroll
            for (int f = 0; f < 2; f++) {
                size_t bi = ((size_t)((nfg0 + f) * 8 + ks) * 64 + lane) * 8;
                short8v bh = *reinterpret_cast<const short8v*>(W2h + bi);
                short8v bl = *reinterpret_cast<const short8v*>(W2l + bi);
                accB[f][0] = MFMA16(ah0, bh, accB[f][0]);
                accB[f][0] = MFMA16(al0, bh, accB[f][0]);
                accB[f][0] = MFMA16(ah0, bl, accB[f][0]);
                accB[f][1] = MFMA16(ah1, bh, accB[f][1]);
                accB[f][1] = MFMA16(al1, bh, accB[f][1]);
                accB[f][1] = MFMA16(ah1, bl, accB[f][1]);
            }
        }
        __builtin_amdgcn_s_setprio(0);
    }
    __syncthreads();                                            // bar 4
    // all C0 reads of m2 done -> safe to overwrite with chunk 1

    {   // B1 store
        #pragma unroll
        for (int f = 0; f < 2; f++)
            #pragma unroll
            for (int m = 0; m < 2; m++)
                store_quad(m2h_, m2l_,
                           fmaxf(accB[f][m][0], 0.f), fmaxf(accB[f][m][1], 0.f),
                           fmaxf(accB[f][m][2], 0.f), fmaxf(accB[f][m][3], 0.f),
                           m * 16 + lq * 4, (2 * w + f) * 16 + lm, 256);
    }
    __syncthreads();                                            // bar 5

    {   // C1: dacc += m2c1[:, kq quarter] @ W3[k 256..511]
        __builtin_amdgcn_s_setprio(1);
        #pragma unroll
        for (int kl = 0; kl < 4; kl++) {
            int ksl = kq * 4 + kl;
            short8v ah0 = *reinterpret_cast<const short8v*>(&m2h_[swz(lm, ksl * 32 + lq * 8, 256)]);
            short8v al0 = *reinterpret_cast<const short8v*>(&m2l_[swz(lm, ksl * 32 + lq * 8, 256)]);
            short8v ah1 = *reinterpret_cast<const short8v*>(&m2h_[swz(16 + lm, ksl * 32 + lq * 8, 256)]);
            short8v al1 = *reinterpret_cast<const short8v*>(&m2l_[swz(16 + lm, ksl * 32 + lq * 8, 256)]);
            size_t bi = ((size_t)(nfc * 16 + 8 + ksl) * 64 + lane) * 8;
            short8v ch = *reinterpret_cast<const short8v*>(W3h + bi);
            short8v cl = *reinterpret_cast<const short8v*>(W3l + bi);
            dacc[0] = MFMA16(ah0, ch, dacc[0]);
            dacc[0] = MFMA16(al0, ch, dacc[0]);
            dacc[0] = MFMA16(ah0, cl, dacc[0]);
            dacc[1] = MFMA16(ah1, ch, dacc[1]);
            dacc[1] = MFMA16(al1, ch, dacc[1]);
            dacc[1] = MFMA16(ah1, cl, dacc[1]);
        }
        __builtin_amdgcn_s_setprio(0);
    }

    // ---- combine kq halves via fp32 scratch (m1 region; m1 reads ended bar4)
    if (kq == 1) {
        #pragma unroll
        for (int m = 0; m < 2; m++)
            #pragma unroll
            for (int r = 0; r < 4; r++)
                scr[(m * 16 + lq * 4 + r) * 64 + nfc * 16 + lm] = dacc[m][r];
    }
    __syncthreads();                                            // bar 6
    if (kq == 0) {
        #pragma unroll
        for (int m = 0; m < 2; m++)
            #pragma unroll
            for (int r = 0; r < 4; r++) {
                int rr = base + m * 16 + lq * 4 + r;
                float dv = dacc[m][r] + scr[(m * 16 + lq * 4 + r) * 64 + nfc * 16 + lm];
                size_t gi = (size_t)rr * 64 + nfc * 16 + lm;
                h[gi] = h[gi] + (float)cnt[rr] * dv;
            }
    }
}

// ---------------- precompute score vectors (fp32) ---------------------------
__global__ __launch_bounds__(256) void prec_kernel(
    const float* __restrict__ q, const float* __restrict__ W_in,
    const float* __restrict__ b_in, const float* __restrict__ Wp,
    const float* __restrict__ bp, float* __restrict__ prec)
{
    __shared__ float qh_s[256];
    __shared__ float u_s[4 * 256];
    const int tid = threadIdx.x;
    {
        float acc = b_in[tid];
        for (int j = 0; j < 256; j++) acc += q[j] * W_in[j * 768 + tid];
        qh_s[tid] = acc * 0.125f;
    }
    __syncthreads();
    {
        #pragma unroll
        for (int hd = 0; hd < 4; hd++) {
            float a = 0.f;
            for (int d = 0; d < 64; d++)
                a += W_in[tid * 768 + 256 + hd * 64 + d] * qh_s[hd * 64 + d];
            u_s[hd * 256 + tid] = a;
        }
    }
    __syncthreads();
    {
        int hd = tid >> 6, i = tid & 63;
        float a = 0.f;
        for (int j = 0; j < 256; j++) a += Wp[i * 256 + j] * u_s[hd * 256 + j];
        prec[hd * 64 + i] = a;
    }
    if (tid < 4) {
        float a = 0.f;
        for (int j = 0; j < 256; j++) a += bp[j] * u_s[tid * 256 + j];
        for (int d = 0; d < 64; d++) a += b_in[256 + tid * 64 + d] * qh_s[tid * 64 + d];
        prec[256 + tid] = a;
    }
}

// ---------------- attention pooling (fp32) ----------------------------------
__global__ __launch_bounds__(64) void attnpool_kernel(
    const float* __restrict__ h, const float* __restrict__ prec,
    float* __restrict__ hw)
{
    __shared__ float hs[48 * 65];
    __shared__ float ss[4 * 64];
    __shared__ float ds_[4];
    __shared__ float wl[48 * 4];
    const int lane = threadIdx.x;
    const int g = blockIdx.x;
    #pragma unroll
    for (int hd = 0; hd < 4; hd++) ss[hd * 64 + lane] = prec[hd * 64 + lane];
    if (lane < 4) ds_[lane] = prec[256 + lane];
    for (int r = 0; r < 48; r++)
        hs[r * 65 + lane] = h[((size_t)g * 48 + r) * 64 + lane];
    __syncthreads();
    float sc[4] = {0.f, 0.f, 0.f, 0.f};
    if (lane < 48) {
        #pragma unroll
        for (int hd = 0; hd < 4; hd++) sc[hd] = ds_[hd];
        for (int c = 0; c < 64; c++) {
            float a = hs[lane * 65 + c];
            #pragma unroll
            for (int hd = 0; hd < 4; hd++) sc[hd] += a * ss[hd * 64 + c];
        }
    }
    #pragma unroll
    for (int hd = 0; hd < 4; hd++) {
        float v = (lane < 48) ? sc[hd] : -3.0e38f;
        #pragma unroll
        for (int m = 32; m >= 1; m >>= 1) v = fmaxf(v, __shfl_xor(v, m, 64));
        float e = (lane < 48) ? __expf(sc[hd] - v) : 0.f;
        float s = e;
        #pragma unroll
        for (int m = 32; m >= 1; m >>= 1) s += __shfl_xor(s, m, 64);
        if (lane < 48) wl[lane * 4 + hd] = e / s;
    }
    __syncthreads();
    float acc[4] = {0.f, 0.f, 0.f, 0.f};
    for (int n = 0; n < 48; n++) {
        float hv = hs[n * 65 + lane];
        #pragma unroll
        for (int hd = 0; hd < 4; hd++) acc[hd] += wl[n * 4 + hd] * hv;
    }
    #pragma unroll
    for (int hd = 0; hd < 4; hd++) hw[(size_t)g * 256 + hd * 64 + lane] = acc[hd];
}

// ---------------- tail stage helper: [32x256] @ [256x256] split-bf16 --------
__device__ __forceinline__ void tail_stage(
    const unsigned short* __restrict__ inh, const unsigned short* __restrict__ inl,
    const unsigned short* __restrict__ wh, const unsigned short* __restrict__ wl,
    const float* __restrict__ bias, const bool do_relu,
    unsigned short* __restrict__ oth, unsigned short* __restrict__ otl,
    float* __restrict__ tf32,
    const int w, const int lane, const int lm, const int lq)
{
    f32x4 acc[2][2];
    #pragma unroll
    for (int f = 0; f < 2; f++) {
        float bv = bias[(2 * w + f) * 16 + lm];
        acc[f][0] = f32x4{bv, bv, bv, bv};
        acc[f][1] = acc[f][0];
    }
    #pragma unroll
    for (int ks = 0; ks < 8; ks++) {
        short8v ah0 = *reinterpret_cast<const short8v*>(&inh[swz(lm, ks * 32 + lq * 8, 256)]);
        short8v al0 = *reinterpret_cast<const short8v*>(&inl[swz(lm, ks * 32 + lq * 8, 256)]);
        short8v ah1 = *reinterpret_cast<const short8v*>(&inh[swz(16 + lm, ks * 32 + lq * 8, 256)]);
        short8v al1 = *reinterpret_cast<const short8v*>(&inl[swz(16 + lm, ks * 32 + lq * 8, 256)]);
        #pragma unroll
        for (int f = 0; f < 2; f++) {
            size_t bi = ((size_t)((2 * w + f) * 8 + ks) * 64 + lane) * 8;
            short8v bh = *reinterpret_cast<const short8v*>(wh + bi);
            short8v bl = *reinterpret_cast<const short8v*>(wl + bi);
            acc[f][0] = MFMA16(ah0, bh, acc[f][0]);
            acc[f][0] = MFMA16(al0, bh, acc[f][0]);
            acc[f][0] = MFMA16(ah0, bl, acc[f][0]);
            acc[f][1] = MFMA16(ah1, bh, acc[f][1]);
            acc[f][1] = MFMA16(al1, bh, acc[f][1]);
            acc[f][1] = MFMA16(ah1, bl, acc[f][1]);
        }
    }
    #pragma unroll
    for (int f = 0; f < 2; f++)
        #pragma unroll
        for (int m = 0; m < 2; m++) {
            if (tf32) {
                #pragma unroll
                for (int r = 0; r < 4; r++) {
                    float v = acc[f][m][r];
                    if (do_relu) v = fmaxf(v, 0.f);
                    tf32[(m * 16 + lq * 4 + r) * 256 + (2 * w + f) * 16 + lm] = v;
                }
            } else {
                float v0 = acc[f][m][0], v1 = acc[f][m][1], v2 = acc[f][m][2], v3 = acc[f][m][3];
                if (do_relu) {
                    v0 = fmaxf(v0, 0.f); v1 = fmaxf(v1, 0.f);
                    v2 = fmaxf(v2, 0.f); v3 = fmaxf(v3, 0.f);
                }
                store_quad(oth, otl, v0, v1, v2, v3,
                           m * 16 + lq * 4, (2 * w + f) * 16 + lm, 256);
            }
        }
}

// ---------------- fused MFMA tail: pooled->attn->t->LN->out -----------------
__global__ __launch_bounds__(512, 4) void tail_mfma_kernel(
    const float* __restrict__ hw,
    const unsigned short* __restrict__ Gh, const unsigned short* __restrict__ Gl,
    const float* __restrict__ Gd,
    const unsigned short* __restrict__ Woh, const unsigned short* __restrict__ Wol,
    const float* __restrict__ b_out,
    const unsigned short* __restrict__ Wh1h, const unsigned short* __restrict__ Wh1l,
    const float* __restrict__ bh1,
    const float* __restrict__ ln_g, const float* __restrict__ ln_b,
    const unsigned short* __restrict__ Wh2h, const unsigned short* __restrict__ Wh2l,
    const float* __restrict__ bh2,
    float* __restrict__ out)
{
    __shared__ __attribute__((aligned(16))) unsigned short L[32768];
    unsigned short* Ah = L;
    unsigned short* Al = L + 8192;
    unsigned short* Bh = L + 16384;
    unsigned short* Bl = L + 24576;
    float* tf = reinterpret_cast<float*>(L + 16384);
    const int tid = threadIdx.x;
    const int lane = tid & 63, w = tid >> 6;
    const int lm = lane & 15, lq = lane >> 4;
    const int g0 = blockIdx.x * 32;

    {   // load hw tile [32x256] -> A hi/lo swizzled
        const float4* hp = reinterpret_cast<const float4*>(hw + (size_t)g0 * 256);
        #pragma unroll
        for (int i = 0; i < 4; i++) {
            int e = tid + 512 * i;
            int row = e >> 6, c0 = (e & 63) * 4;
            float4 u = hp[e];
            unsigned int p01 = cvtpk(u.x, u.y);
            unsigned int p23 = cvtpk(u.z, u.w);
            float h0 = __uint_as_float(p01 << 16), h1 = __uint_as_float(p01 & 0xffff0000u);
            float h2 = __uint_as_float(p23 << 16), h3 = __uint_as_float(p23 & 0xffff0000u);
            unsigned int q01 = cvtpk(u.x - h0, u.y - h1);
            unsigned int q23 = cvtpk(u.z - h2, u.w - h3);
            int idx = swz(row, c0, 256);
            *reinterpret_cast<uint2*>(&Ah[idx]) = make_uint2(p01, p23);
            *reinterpret_cast<uint2*>(&Al[idx]) = make_uint2(q01, q23);
        }
    }
    __syncthreads();
    tail_stage(Ah, Al, Gh, Gl, Gd, false, Bh, Bl, nullptr, w, lane, lm, lq);
    __syncthreads();
    tail_stage(Bh, Bl, Woh, Wol, b_out, true, Ah, Al, nullptr, w, lane, lm, lq);
    __syncthreads();
    tail_stage(Ah, Al, Wh1h, Wh1l, bh1, true, nullptr, nullptr, tf, w, lane, lm, lq);
    __syncthreads();
    {   // LN per row (16 threads per row), write normalized bf16 hi/lo -> A
        const int row = tid >> 4, l16 = tid & 15;
        float s = 0.f;
        #pragma unroll
        for (int k = 0; k < 16; k++) s += tf[row * 256 + l16 + 16 * k];
        #pragma unroll
        for (int m = 1; m < 16; m <<= 1) s += __shfl_xor(s, m, 16);
        float mu = s * (1.f / 256.f);
        float v = 0.f;
        #pragma unroll
        for (int k = 0; k < 16; k++) {
            float d = tf[row * 256 + l16 + 16 * k] - mu;
            v += d * d;
        }
        #pragma unroll
        for (int m = 1; m < 16; m <<= 1) v += __shfl_xor(v, m, 16);
        float rs = rsqrtf(v * (1.f / 256.f) + 1e-5f);
        #pragma unroll
        for (int k = 0; k < 16; k++) {
            int col = l16 + 16 * k;
            float val = (tf[row * 256 + col] - mu) * rs * ln_g[col] + ln_b[col];
            unsigned short hi = f2bf(val);
            int idx = swz(row, col, 256);
            Ah[idx] = hi;
            Al[idx] = f2bf(val - bf2f(hi));
        }
    }
    __syncthreads();
    {   // S: out = t @ Wh2 + bh2   [32x256]@[256x1024]
        f32x4 acc[8][2];
        #pragma unroll
        for (int f = 0; f < 8; f++) {
            float bv = bh2[(8 * w + f) * 16 + lm];
            acc[f][0] = f32x4{bv, bv, bv, bv};
            acc[f][1] = acc[f][0];
        }
        #pragma unroll
        for (int ks = 0; ks < 8; ks++) {
            short8v ah0 = *reinterpret_cast<const short8v*>(&Ah[swz(lm, ks * 32 + lq * 8, 256)]);
            short8v al0 = *reinterpret_cast<const short8v*>(&Al[swz(lm, ks * 32 + lq * 8, 256)]);
            short8v ah1 = *reinterpret_cast<const short8v*>(&Ah[swz(16 + lm, ks * 32 + lq * 8, 256)]);
            short8v al1 = *reinterpret_cast<const short8v*>(&Al[swz(16 + lm, ks * 32 + lq * 8, 256)]);
            #pragma unroll
            for (int f = 0; f < 8; f++) {
                size_t bi = ((size_t)((8 * w + f) * 8 + ks) * 64 + lane) * 8;
                short8v bh = *reinterpret_cast<const short8v*>(Wh2h + bi);
                short8v bl = *reinterpret_cast<const short8v*>(Wh2l + bi);
                acc[f][0] = MFMA16(ah0, bh, acc[f][0]);
                acc[f][0] = MFMA16(al0, bh, acc[f][0]);
                acc[f][0] = MFMA16(ah0, bl, acc[f][0]);
                acc[f][1] = MFMA16(ah1, bh, acc[f][1]);
                acc[f][1] = MFMA16(al1, bh, acc[f][1]);
                acc[f][1] = MFMA16(ah1, bl, acc[f][1]);
            }
        }
        #pragma unroll
        for (int f = 0; f < 8; f++)
            #pragma unroll
            for (int m = 0; m < 2; m++)
                #pragma unroll
                for (int r = 0; r < 4; r++)
                    out[(size_t)(g0 + m * 16 + lq * 4 + r) * 1024 + (8 * w + f) * 16 + lm]
                        = acc[f][m][r];
    }
}

extern "C" void kernel_launch(void* const* d_in, const int* in_sizes, int n_in,
                              void* d_out, int out_size, void* d_ws, size_t ws_size,
                              hipStream_t stream) {
    const float* x       = (const float*)d_in[0];
    const int*   edge    = (const int*)d_in[1];
    const float* W_embed = (const float*)d_in[3];
    const float* b_embed = (const float*)d_in[4];
    const float* W1 = (const float*)d_in[5];
    const float* b1 = (const float*)d_in[6];
    const float* W2 = (const float*)d_in[7];
    const float* b2 = (const float*)d_in[8];
    const float* W3 = (const float*)d_in[9];
    const float* b3 = (const float*)d_in[10];
    const float* Wp = (const float*)d_in[11];
    const float* bp = (const float*)d_in[12];
    const float* q  = (const float*)d_in[13];
    const float* W_in  = (const float*)d_in[14];
    const float* b_in  = (const float*)d_in[15];
    const float* W_out = (const float*)d_in[16];
    const float* b_out = (const float*)d_in[17];
    const float* Wh1 = (const float*)d_in[18];
    const float* bh1 = (const float*)d_in[19];
    const float* ln_g = (const float*)d_in[20];
    const float* ln_b = (const float*)d_in[21];
    const float* Wh2 = (const float*)d_in[22];
    const float* bh2 = (const float*)d_in[23];
    float* out = (float*)d_out;

    char* ws = (char*)d_ws;
    int*   cnt  = (int*)(ws + 0);
    float* h    = (float*)(ws + 393216);
    float* hw   = (float*)(ws + 25559040);
    float* prec = (float*)(ws + 27656192);
    unsigned short* W1h = (unsigned short*)(ws + 27657232);
    unsigned short* W1l = (unsigned short*)(ws + 27853840);
    unsigned short* W2h = (unsigned short*)(ws + 28050448);
    unsigned short* W2l = (unsigned short*)(ws + 29623312);
    unsigned short* W3h = (unsigned short*)(ws + 31196176);
    unsigned short* W3l = (unsigned short*)(ws + 31589392);
    unsigned short* Weh = (unsigned short*)(ws + 31982608);
    unsigned short* Wel = (unsigned short*)(ws + 31998992);
    float* Gm  = (float*)(ws + 32015376);
    float* Gd  = (float*)(ws + 32277520);
    unsigned short* Gfh  = (unsigned short*)(ws + 32278544);
    unsigned short* Gfl  = (unsigned short*)(ws + 32409616);
    unsigned short* Wofh = (unsigned short*)(ws + 32540688);
    unsigned short* Wofl = (unsigned short*)(ws + 32671760);
    unsigned short* Wh1fh= (unsigned short*)(ws + 32802832);
    unsigned short* Wh1fl= (unsigned short*)(ws + 32933904);
    unsigned short* Wh2fh= (unsigned short*)(ws + 33064976);
    unsigned short* Wh2fl= (unsigned short*)(ws + 33589264);

    zero_cnt_kernel<<<N_NODES / 256, 256, 0, stream>>>(cnt);
    hist_kernel<<<N_EDGES / 256, 256, 0, stream>>>(edge, cnt);

    prep_frag_kernel<<<1 * (64 / 16) * (128 / 32), 64, 0, stream>>>(W_embed, Weh, Wel, 128, 64);
    prep_frag_kernel<<<6 * (256 / 16) * (64 / 32), 64, 0, stream>>>(W1, W1h, W1l, 64, 256);
    prep_frag_kernel<<<6 * (512 / 16) * (256 / 32), 64, 0, stream>>>(W2, W2h, W2l, 256, 512);
    prep_frag_kernel<<<6 * (64 / 16) * (512 / 32), 64, 0, stream>>>(W3, W3h, W3l, 512, 64);

    gbuild_kernel<<<256, 256, 0, stream>>>(Wp, bp, W_in, b_in, Gm, Gd);
    prep_frag_kernel<<<(256 / 16) * (256 / 32), 64, 0, stream>>>(Gm, Gfh, Gfl, 256, 256);
    prep_frag_kernel<<<(256 / 16) * (256 / 32), 64, 0, stream>>>(W_out, Wofh, Wofl, 256, 256);
    prep_frag_kernel<<<(256 / 16) * (256 / 32), 64, 0, stream>>>(Wh1, Wh1fh, Wh1fl, 256, 256);
    prep_frag_kernel<<<(1024 / 16) * (256 / 32), 64, 0, stream>>>(Wh2, Wh2fh, Wh2fl, 256, 1024);

    embed_mfma_kernel<<<N_NODES / 32, 256, 0, stream>>>(x, Weh, Wel, b_embed, h);
    for (int l = 0; l < N_LAYERS_; l++) {
        layer_mfma_kernel<<<N_NODES / 32, 512, 0, stream>>>(
            h, cnt,
            W1h + (size_t)l * EMB * HID,     W1l + (size_t)l * EMB * HID,     b1 + (size_t)l * HID,
            W2h + (size_t)l * HID * 2 * HID, W2l + (size_t)l * HID * 2 * HID, b2 + (size_t)l * 2 * HID,
            W3h + (size_t)l * 2 * HID * EMB, W3l + (size_t)l * 2 * HID * EMB, b3 + (size_t)l * EMB);
    }
    prec_kernel<<<1, 256, 0, stream>>>(q, W_in, b_in, Wp, bp, prec);
    attnpool_kernel<<<N_GRAPHS, 64, 0, stream>>>(h, prec, hw);
    tail_mfma_kernel<<<N_GRAPHS / 32, 512, 0, stream>>>(
        hw, Gfh, Gfl, Gd, Wofh, Wofl, b_out, Wh1fh, Wh1fl, bh1,
        ln_g, ln_b, Wh2fh, Wh2fl, bh2, out);
}

// Round 14
// 850.123 us; speedup vs baseline: 1.0180x; 1.0180x over previous
//
#include <hip/hip_runtime.h>
#include <hip/hip_bf16.h>

#define N_NODES 98304
#define N_GRAPHS 2048
#define N_EDGES 393216
#define EMB 64
#define HID 256
#define N_LAYERS_ 6

typedef __attribute__((ext_vector_type(8))) short short8v;
typedef __attribute__((ext_vector_type(4))) float f32x4;
#define MFMA16(a, b, c) __builtin_amdgcn_mfma_f32_16x16x32_bf16(a, b, c, 0, 0, 0)

__device__ __forceinline__ unsigned short f2bf(float x) {
    unsigned int u = __float_as_uint(x);
    u = (u + 0x7fffu + ((u >> 16) & 1u)) >> 16;
    return (unsigned short)u;
}
__device__ __forceinline__ float bf2f(unsigned short h) {
    return __uint_as_float(((unsigned int)h) << 16);
}
// pack 2 floats -> 2 bf16 (RNE): low16 = a, high16 = b
__device__ __forceinline__ unsigned int cvtpk(float a, float b) {
    unsigned int r;
    asm("v_cvt_pk_bf16_f32 %0, %1, %2" : "=v"(r) : "v"(a), "v"(b));
    return r;
}
// swizzled index (ushort units): XOR 16B-slot id with low row bits (bijective)
__device__ __forceinline__ int swz(int row, int col, int rowc) {
    return (row * rowc + col) ^ ((row & ((rowc >> 3) - 1)) << 3);
}

// ---------------- histogram of edge rows ----------------
__global__ __launch_bounds__(256) void zero_cnt_kernel(int* __restrict__ cnt) {
    int i = blockIdx.x * 256 + threadIdx.x;
    if (i < N_NODES) cnt[i] = 0;
}
__global__ __launch_bounds__(256) void hist_kernel(const int* __restrict__ row,
                                                   int* __restrict__ cnt) {
    int i = blockIdx.x * 256 + threadIdx.x;
    if (i < N_EDGES) atomicAdd(&cnt[row[i]], 1);
}

// ---------------- weight prep: fp32 [L][K][N] -> hi/lo bf16 MFMA B-frags ----
__global__ __launch_bounds__(64) void prep_frag_kernel(
    const float* __restrict__ W, unsigned short* __restrict__ oh,
    unsigned short* __restrict__ ol, int K, int N)
{
    const int NF = N >> 4, KS = K >> 5;
    const int fpl = NF * KS;
    const int layer = blockIdx.x / fpl;
    const int fid = blockIdx.x % fpl;
    const int nf = fid / KS, ks = fid % KS;
    const int lane = threadIdx.x;
    const float* Wl = W + (size_t)layer * K * N;
    const int n = nf * 16 + (lane & 15);
    const int kb = ks * 32 + (lane >> 4) * 8;
    short8v vh, vl;
    #pragma unroll
    for (int j = 0; j < 8; j++) {
        float wv = Wl[(size_t)(kb + j) * N + n];
        unsigned short hi = f2bf(wv);
        vh[j] = (short)hi;
        vl[j] = (short)f2bf(wv - bf2f(hi));
    }
    size_t o = (size_t)layer * K * N + ((size_t)(nf * KS + ks) * 64 + lane) * 8;
    *reinterpret_cast<short8v*>(oh + o) = vh;
    *reinterpret_cast<short8v*>(ol + o) = vl;
}

// ---------------- G = per-head (Wp @ Wv) fold + d vector --------------------
__global__ __launch_bounds__(256) void gbuild_kernel(
    const float* __restrict__ Wp, const float* __restrict__ bp,
    const float* __restrict__ W_in, const float* __restrict__ b_in,
    float* __restrict__ Gm, float* __restrict__ Gd)
{
    const int idx = blockIdx.x * 256 + threadIdx.x;
    const int q = idx >> 8, p = idx & 255;
    float s = 0.f;
    if ((q >> 6) == (p >> 6)) {
        const float* wr = Wp + (q & 63) * 256;
        for (int j = 0; j < 256; j++) s += wr[j] * W_in[j * 768 + 512 + p];
    }
    Gm[q * 256 + p] = s;
    if (blockIdx.x == 0) {
        const int pp = threadIdx.x;
        float dsum = b_in[512 + pp];
        for (int j = 0; j < 256; j++) dsum += bp[j] * W_in[j * 768 + 512 + pp];
        Gd[pp] = dsum;
    }
}

// ---------------- embed via split MFMA: h = x @ W_embed + b -----------------
__global__ __launch_bounds__(256) void embed_mfma_kernel(
    const float* __restrict__ x,
    const unsigned short* __restrict__ Weh, const unsigned short* __restrict__ Wel,
    const float* __restrict__ b, float* __restrict__ h)
{
    __shared__ __attribute__((aligned(16))) unsigned short xh[32 * 128];
    __shared__ __attribute__((aligned(16))) unsigned short xl[32 * 128];
    const int tid = threadIdx.x;
    const int lane = tid & 63, w = tid >> 6;
    const int lm = lane & 15, lq = lane >> 4;
    const int base = blockIdx.x * 32;
    {
        int row = tid >> 3, c0 = (tid & 7) * 16;
        const float4* p = reinterpret_cast<const float4*>(x + (size_t)(base + row) * 128 + c0);
        #pragma unroll
        for (int g = 0; g < 4; g++) {
            float4 u = p[g];
            unsigned int p01 = cvtpk(u.x, u.y);
            unsigned int p23 = cvtpk(u.z, u.w);
            float h0 = __uint_as_float(p01 << 16), h1 = __uint_as_float(p01 & 0xffff0000u);
            float h2 = __uint_as_float(p23 << 16), h3 = __uint_as_float(p23 & 0xffff0000u);
            unsigned int q01 = cvtpk(u.x - h0, u.y - h1);
            unsigned int q23 = cvtpk(u.z - h2, u.w - h3);
            int idx = swz(row, c0 + g * 4, 128);
            *reinterpret_cast<uint2*>(&xh[idx]) = make_uint2(p01, p23);
            *reinterpret_cast<uint2*>(&xl[idx]) = make_uint2(q01, q23);
        }
    }
    __syncthreads();
    f32x4 acc0, acc1;
    {
        float bv = b[w * 16 + lm];
        acc0 = f32x4{bv, bv, bv, bv};
        acc1 = acc0;
    }
    #pragma unroll
    for (int ks = 0; ks < 4; ks++) {
        short8v a0h = *reinterpret_cast<const short8v*>(&xh[swz(lm, ks * 32 + lq * 8, 128)]);
        short8v a0l = *reinterpret_cast<const short8v*>(&xl[swz(lm, ks * 32 + lq * 8, 128)]);
        short8v a1h = *reinterpret_cast<const short8v*>(&xh[swz(16 + lm, ks * 32 + lq * 8, 128)]);
        short8v a1l = *reinterpret_cast<const short8v*>(&xl[swz(16 + lm, ks * 32 + lq * 8, 128)]);
        size_t bi = ((size_t)(w * 4 + ks) * 64 + lane) * 8;
        short8v bh = *reinterpret_cast<const short8v*>(Weh + bi);
        short8v bl = *reinterpret_cast<const short8v*>(Wel + bi);
        acc0 = MFMA16(a0h, bh, acc0); acc0 = MFMA16(a0l, bh, acc0); acc0 = MFMA16(a0h, bl, acc0);
        acc1 = MFMA16(a1h, bh, acc1); acc1 = MFMA16(a1l, bh, acc1); acc1 = MFMA16(a1h, bl, acc1);
    }
    #pragma unroll
    for (int r = 0; r < 4; r++) {
        h[(size_t)(base + lq * 4 + r) * 64 + w * 16 + lm] = acc0[r];
        h[(size_t)(base + 16 + lq * 4 + r) * 64 + w * 16 + lm] = acc1[r];
    }
}

// ---- helper: split-convert 4 row-consecutive values, store hi/lo to LDS ----
__device__ __forceinline__ void store_quad(
    unsigned short* __restrict__ oh, unsigned short* __restrict__ ol,
    float v0, float v1, float v2, float v3,
    int row0, int col, int rowc)
{
    unsigned int p01 = cvtpk(v0, v1);
    unsigned int p23 = cvtpk(v2, v3);
    float h0 = __uint_as_float(p01 << 16), h1 = __uint_as_float(p01 & 0xffff0000u);
    float h2 = __uint_as_float(p23 << 16), h3 = __uint_as_float(p23 & 0xffff0000u);
    unsigned int q01 = cvtpk(v0 - h0, v1 - h1);
    unsigned int q23 = cvtpk(v2 - h2, v3 - h3);
    oh[swz(row0 + 0, col, rowc)] = (unsigned short)p01;
    oh[swz(row0 + 1, col, rowc)] = (unsigned short)(p01 >> 16);
    oh[swz(row0 + 2, col, rowc)] = (unsigned short)p23;
    oh[swz(row0 + 3, col, rowc)] = (unsigned short)(p23 >> 16);
    ol[swz(row0 + 0, col, rowc)] = (unsigned short)q01;
    ol[swz(row0 + 1, col, rowc)] = (unsigned short)(q01 >> 16);
    ol[swz(row0 + 2, col, rowc)] = (unsigned short)q23;
    ol[swz(row0 + 3, col, rowc)] = (unsigned short)(q23 >> 16);
}

// ---------------- fused MLP layer, v11: R12 config + balanced epilogue ------
// 32 nodes/block, 8 waves, LDS 64KB -> 2 blocks/CU. Double-buffered m2:
// one barrier per chunk; waves drift across C(c) and B(c+1). setprio on MFMA.
__global__ __launch_bounds__(512, 4) void layer_mfma_kernel(
    float* __restrict__ h, const int* __restrict__ cnt,
    const unsigned short* __restrict__ W1h, const unsigned short* __restrict__ W1l,
    const float* __restrict__ b1,
    const unsigned short* __restrict__ W2h, const unsigned short* __restrict__ W2l,
    const float* __restrict__ b2,
    const unsigned short* __restrict__ W3h, const unsigned short* __restrict__ W3l,
    const float* __restrict__ b3)
{
    __shared__ __attribute__((aligned(16))) unsigned short m1h_[8192];  // 16KB
    __shared__ __attribute__((aligned(16))) unsigned short m1l_[8192];  // 16KB
    __shared__ __attribute__((aligned(16))) unsigned short m2b_[16384]; // 2 bufs x 16KB
    unsigned short* hsh = m2b_;          // 32x64, dead after stage A (buf0 region)
    unsigned short* hsl = m2b_ + 2048;
    const int tid = threadIdx.x;
    const int lane = tid & 63, w = tid >> 6;
    const int lm = lane & 15, lq = lane >> 4;
    const int base = blockIdx.x * 32;

    // issue stage-0 global load first (longest chain)
    int s0row = tid >> 4, s0c = (tid & 15) * 4;
    const float4 u0 = *reinterpret_cast<const float4*>(h + (size_t)(base + s0row) * 64 + s0c);

    // stage-A weight preload: frag indices 4w + (2f+ks)
    const unsigned short* pAh = W1h + ((size_t)(4 * w) * 64 + lane) * 8;
    const unsigned short* pAl = W1l + ((size_t)(4 * w) * 64 + lane) * 8;
    short8v awh[4], awl[4];
    #pragma unroll
    for (int i = 0; i < 4; i++) {
        awh[i] = *reinterpret_cast<const short8v*>(pAh + (size_t)i * 512);
        awl[i] = *reinterpret_cast<const short8v*>(pAl + (size_t)i * 512);
    }

    {   // stage 0: h tile (fp32 32x64) -> hi/lo bf16 planes
        unsigned int p01 = cvtpk(u0.x, u0.y);
        unsigned int p23 = cvtpk(u0.z, u0.w);
        float h0 = __uint_as_float(p01 << 16), h1 = __uint_as_float(p01 & 0xffff0000u);
        float h2 = __uint_as_float(p23 << 16), h3 = __uint_as_float(p23 & 0xffff0000u);
        unsigned int q01 = cvtpk(u0.x - h0, u0.y - h1);
        unsigned int q23 = cvtpk(u0.z - h2, u0.w - h3);
        int idx = swz(s0row, s0c, 64);
        *reinterpret_cast<uint2*>(&hsh[idx]) = make_uint2(p01, p23);
        *reinterpret_cast<uint2*>(&hsl[idx]) = make_uint2(q01, q23);
    }
    __syncthreads();                                            // barrier 1

    // ---- stage A: m1 = relu(hs @ W1 + b1)  [32x256]; wave w -> frags {2w,2w+1}
    {
        f32x4 acc[2][2];   // [f][m]
        #pragma unroll
        for (int f = 0; f < 2; f++) {
            float bv = b1[(2 * w + f) * 16 + lm];
            acc[f][0] = f32x4{bv, bv, bv, bv};
            acc[f][1] = acc[f][0];
        }
        __builtin_amdgcn_s_setprio(1);
        #pragma unroll
        for (int ks = 0; ks < 2; ks++) {
            short8v ah0 = *reinterpret_cast<const short8v*>(&hsh[swz(lm, ks * 32 + lq * 8, 64)]);
            short8v al0 = *reinterpret_cast<const short8v*>(&hsl[swz(lm, ks * 32 + lq * 8, 64)]);
            short8v ah1 = *reinterpret_cast<const short8v*>(&hsh[swz(16 + lm, ks * 32 + lq * 8, 64)]);
            short8v al1 = *reinterpret_cast<const short8v*>(&hsl[swz(16 + lm, ks * 32 + lq * 8, 64)]);
            #pragma unroll
            for (int f = 0; f < 2; f++) {
                short8v bh = awh[2 * f + ks];
                short8v bl = awl[2 * f + ks];
                acc[f][0] = MFMA16(ah0, bh, acc[f][0]);
                acc[f][0] = MFMA16(al0, bh, acc[f][0]);
                acc[f][0] = MFMA16(ah0, bl, acc[f][0]);
                acc[f][1] = MFMA16(ah1, bh, acc[f][1]);
                acc[f][1] = MFMA16(al1, bh, acc[f][1]);
                acc[f][1] = MFMA16(ah1, bl, acc[f][1]);
            }
        }
        __builtin_amdgcn_s_setprio(0);
        #pragma unroll
        for (int f = 0; f < 2; f++)
            #pragma unroll
            for (int m = 0; m < 2; m++)
                store_quad(m1h_, m1l_,
                           fmaxf(acc[f][m][0], 0.f), fmaxf(acc[f][m][1], 0.f),
                           fmaxf(acc[f][m][2], 0.f), fmaxf(acc[f][m][3], 0.f),
                           m * 16 + lq * 4, (2 * w + f) * 16 + lm, 256);
    }
    __syncthreads();                                            // barrier 2

    // persistent stage-C accumulators: wave -> nfc = w&3 (cols), kq = w>>2 (k-half)
    const int nfc = w & 3, kq = w >> 2;
    f32x4 dacc[2];
    if (kq == 0) {
        float bv = b3[nfc * 16 + lm];
        dacc[0] = f32x4{bv, bv, bv, bv};
    } else {
        dacc[0] = f32x4{0.f, 0.f, 0.f, 0.f};
    }
    dacc[1] = dacc[0];

    #pragma unroll
    for (int c = 0; c < 4; ++c) {
        unsigned short* m2h_ = m2b_ + (c & 1) * 8192;
        unsigned short* m2l_ = m2h_ + 4096;
        short8v cwh[2], cwl[2];   // stage-C weights, hoisted before barrier
        // ---- stage B: m2c = relu(m1 @ W2[:, c*128:+128] + b2); wave -> frag w
        {
            const int nfg = c * 8 + w;
            const unsigned short* pBh = W2h + ((size_t)(nfg * 8) * 64 + lane) * 8;
            const unsigned short* pBl = W2l + ((size_t)(nfg * 8) * 64 + lane) * 8;
            f32x4 acc[2];
            {
                float bv = b2[nfg * 16 + lm];
                acc[0] = f32x4{bv, bv, bv, bv};
                acc[1] = acc[0];
            }
            short8v whE = *reinterpret_cast<const short8v*>(pBh);
            short8v wlE = *reinterpret_cast<const short8v*>(pBl);
            short8v whO = *reinterpret_cast<const short8v*>(pBh + 512);
            short8v wlO = *reinterpret_cast<const short8v*>(pBl + 512);
            __builtin_amdgcn_s_setprio(1);
            #pragma unroll
            for (int kp = 0; kp < 4; kp++) {
                const int k0 = 2 * kp;
                short8v whE2, wlE2, whO2, wlO2;
                if (kp < 3) {
                    whE2 = *reinterpret_cast<const short8v*>(pBh + (size_t)(k0 + 2) * 512);
                    wlE2 = *reinterpret_cast<const short8v*>(pBl + (size_t)(k0 + 2) * 512);
                    whO2 = *reinterpret_cast<const short8v*>(pBh + (size_t)(k0 + 3) * 512);
                    wlO2 = *reinterpret_cast<const short8v*>(pBl + (size_t)(k0 + 3) * 512);
                }
                {
                    short8v ah0 = *reinterpret_cast<const short8v*>(&m1h_[swz(lm, k0 * 32 + lq * 8, 256)]);
                    short8v al0 = *reinterpret_cast<const short8v*>(&m1l_[swz(lm, k0 * 32 + lq * 8, 256)]);
                    short8v ah1 = *reinterpret_cast<const short8v*>(&m1h_[swz(16 + lm, k0 * 32 + lq * 8, 256)]);
                    short8v al1 = *reinterpret_cast<const short8v*>(&m1l_[swz(16 + lm, k0 * 32 + lq * 8, 256)]);
                    acc[0] = MFMA16(ah0, whE, acc[0]);
                    acc[0] = MFMA16(al0, whE, acc[0]);
                    acc[0] = MFMA16(ah0, wlE, acc[0]);
                    acc[1] = MFMA16(ah1, whE, acc[1]);
                    acc[1] = MFMA16(al1, whE, acc[1]);
                    acc[1] = MFMA16(ah1, wlE, acc[1]);
                }
                {
                    short8v ah0 = *reinterpret_cast<const short8v*>(&m1h_[swz(lm, (k0 + 1) * 32 + lq * 8, 256)]);
                    short8v al0 = *reinterpret_cast<const short8v*>(&m1l_[swz(lm, (k0 + 1) * 32 + lq * 8, 256)]);
                    short8v ah1 = *reinterpret_cast<const short8v*>(&m1h_[swz(16 + lm, (k0 + 1) * 32 + lq * 8, 256)]);
                    short8v al1 = *reinterpret_cast<const short8v*>(&m1l_[swz(16 + lm, (k0 + 1) * 32 + lq * 8, 256)]);
                    acc[0] = MFMA16(ah0, whO, acc[0]);
                    acc[0] = MFMA16(al0, whO, acc[0]);
                    acc[0] = MFMA16(ah0, wlO, acc[0]);
                    acc[1] = MFMA16(ah1, whO, acc[1]);
                    acc[1] = MFMA16(al1, whO, acc[1]);
                    acc[1] = MFMA16(ah1, wlO, acc[1]);
                }
                if (kp < 3) { whE = whE2; wlE = wlE2; whO = whO2; wlO = wlO2; }
            }
            __builtin_amdgcn_s_setprio(0);
            // hoist stage-C weight loads: they fly during stores + barrier
            #pragma unroll
            for (int kl = 0; kl < 2; kl++) {
                size_t bi = ((size_t)(nfc * 16 + c * 4 + kq * 2 + kl) * 64 + lane) * 8;
                cwh[kl] = *reinterpret_cast<const short8v*>(W3h + bi);
                cwl[kl] = *reinterpret_cast<const short8v*>(W3l + bi);
            }
            #pragma unroll
            for (int m = 0; m < 2; m++)
                store_quad(m2h_, m2l_,
                           fmaxf(acc[m][0], 0.f), fmaxf(acc[m][1], 0.f),
                           fmaxf(acc[m][2], 0.f), fmaxf(acc[m][3], 0.f),
                           m * 16 + lq * 4, w * 16 + lm, 128);
        }
        __syncthreads();                                        // 1 barrier/chunk
        // ---- stage C partial: dacc += m2c[:, kq-half] @ W3 (weights in regs)
        {
            __builtin_amdgcn_s_setprio(1);
            #pragma unroll
            for (int kl = 0; kl < 2; kl++) {
                int ksl = kq * 2 + kl;
                short8v ah0 = *reinterpret_cast<const short8v*>(&m2h_[swz(lm, ksl * 32 + lq * 8, 128)]);
                short8v al0 = *reinterpret_cast<const short8v*>(&m2l_[swz(lm, ksl * 32 + lq * 8, 128)]);
                short8v ah1 = *reinterpret_cast<const short8v*>(&m2h_[swz(16 + lm, ksl * 32 + lq * 8, 128)]);
                short8v al1 = *reinterpret_cast<const short8v*>(&m2l_[swz(16 + lm, ksl * 32 + lq * 8, 128)]);
                dacc[0] = MFMA16(ah0, cwh[kl], dacc[0]);
                dacc[0] = MFMA16(al0, cwh[kl], dacc[0]);
                dacc[0] = MFMA16(ah0, cwl[kl], dacc[0]);
                dacc[1] = MFMA16(ah1, cwh[kl], dacc[1]);
                dacc[1] = MFMA16(al1, cwh[kl], dacc[1]);
                dacc[1] = MFMA16(ah1, cwl[kl], dacc[1]);
            }
            __builtin_amdgcn_s_setprio(0);
        }
    }

    // ---- balanced combine: both kq planes -> fp32 scratch (m1 region) ------
    // m1 last read in B(3) before the chunk-3 barrier; C(3) touches only m2.
    float* scr = reinterpret_cast<float*>(m1h_);   // 4096 f32 = 16KB (2 planes)
    {
        #pragma unroll
        for (int m = 0; m < 2; m++)
            #pragma unroll
            for (int r = 0; r < 4; r++)
                scr[kq * 2048 + (m * 16 + lq * 4 + r) * 64 + nfc * 16 + lm] = dacc[m][r];
    }
    __syncthreads();                                            // final barrier
    {   // all 512 threads: h += cnt * (plane0 + plane1), f32x4 vectorized
        int i0 = tid * 4;
        int row = i0 >> 6, col = i0 & 63;
        int rr = base + row;
        float cv = (float)cnt[rr];
        f32x4 s0 = *reinterpret_cast<f32x4*>(&scr[i0]);
        f32x4 s1 = *reinterpret_cast<f32x4*>(&scr[2048 + i0]);
        float4* hp = reinterpret_cast<float4*>(h + (size_t)rr * 64 + col);
        float4 hv = *hp;
        hv.x += cv * (s0[0] + s1[0]);
        hv.y += cv * (s0[1] + s1[1]);
        hv.z += cv * (s0[2] + s1[2]);
        hv.w += cv * (s0[3] + s1[3]);
        *hp = hv;
    }
}

// ---------------- precompute score vectors (fp32) ---------------------------
__global__ __launch_bounds__(256) void prec_kernel(
    const float* __restrict__ q, const float* __restrict__ W_in,
    const float* __restrict__ b_in, const float* __restrict__ Wp,
    const float* __restrict__ bp, float* __restrict__ prec)
{
    __shared__ float qh_s[256];
    __shared__ float u_s[4 * 256];
    const int tid = threadIdx.x;
    {
        float acc = b_in[tid];
        for (int j = 0; j < 256; j++) acc += q[j] * W_in[j * 768 + tid];
        qh_s[tid] = acc * 0.125f;
    }
    __syncthreads();
    {
        #pragma unroll
        for (int hd = 0; hd < 4; hd++) {
            float a = 0.f;
            for (int d = 0; d < 64; d++)
                a += W_in[tid * 768 + 256 + hd * 64 + d] * qh_s[hd * 64 + d];
            u_s[hd * 256 + tid] = a;
        }
    }
    __syncthreads();
    {
        int hd = tid >> 6, i = tid & 63;
        float a = 0.f;
        for (int j = 0; j < 256; j++) a += Wp[i * 256 + j] * u_s[hd * 256 + j];
        prec[hd * 64 + i] = a;
    }
    if (tid < 4) {
        float a = 0.f;
        for (int j = 0; j < 256; j++) a += bp[j] * u_s[tid * 256 + j];
        for (int d = 0; d < 64; d++) a += b_in[256 + tid * 64 + d] * qh_s[tid * 64 + d];
        prec[256 + tid] = a;
    }
}

// ---------------- attention pooling (fp32) ----------------------------------
__global__ __launch_bounds__(64) void attnpool_kernel(
    const float* __restrict__ h, const float* __restrict__ prec,
    float* __restrict__ hw)
{
    __shared__ float hs[48 * 65];
    __shared__ float ss[4 * 64];
    __shared__ float ds_[4];
    __shared__ float wl[48 * 4];
    const int lane = threadIdx.x;
    const int g = blockIdx.x;
    #pragma unroll
    for (int hd = 0; hd < 4; hd++) ss[hd * 64 + lane] = prec[hd * 64 + lane];
    if (lane < 4) ds_[lane] = prec[256 + lane];
    for (int r = 0; r < 48; r++)
        hs[r * 65 + lane] = h[((size_t)g * 48 + r) * 64 + lane];
    __syncthreads();
    float sc[4] = {0.f, 0.f, 0.f, 0.f};
    if (lane < 48) {
        #pragma unroll
        for (int hd = 0; hd < 4; hd++) sc[hd] = ds_[hd];
        for (int c = 0; c < 64; c++) {
            float a = hs[lane * 65 + c];
            #pragma unroll
            for (int hd = 0; hd < 4; hd++) sc[hd] += a * ss[hd * 64 + c];
        }
    }
    #pragma unroll
    for (int hd = 0; hd < 4; hd++) {
        float v = (lane < 48) ? sc[hd] : -3.0e38f;
        #pragma unroll
        for (int m = 32; m >= 1; m >>= 1) v = fmaxf(v, __shfl_xor(v, m, 64));
        float e = (lane < 48) ? __expf(sc[hd] - v) : 0.f;
        float s = e;
        #pragma unroll
        for (int m = 32; m >= 1; m >>= 1) s += __shfl_xor(s, m, 64);
        if (lane < 48) wl[lane * 4 + hd] = e / s;
    }
    __syncthreads();
    float acc[4] = {0.f, 0.f, 0.f, 0.f};
    for (int n = 0; n < 48; n++) {
        float hv = hs[n * 65 + lane];
        #pragma unroll
        for (int hd = 0; hd < 4; hd++) acc[hd] += wl[n * 4 + hd] * hv;
    }
    #pragma unroll
    for (int hd = 0; hd < 4; hd++) hw[(size_t)g * 256 + hd * 64 + lane] = acc[hd];
}

// ---------------- tail stage helper: [32x256] @ [256x256] split-bf16 --------
__device__ __forceinline__ void tail_stage(
    const unsigned short* __restrict__ inh, const unsigned short* __restrict__ inl,
    const unsigned short* __restrict__ wh, const unsigned short* __restrict__ wl,
    const float* __restrict__ bias, const bool do_relu,
    unsigned short* __restrict__ oth, unsigned short* __restrict__ otl,
    float* __restrict__ tf32,
    const int w, const int lane, const int lm, const int lq)
{
    f32x4 acc[2][2];
    #pragma unroll
    for (int f = 0; f < 2; f++) {
        float bv = bias[(2 * w + f) * 16 + lm];
        acc[f][0] = f32x4{bv, bv, bv, bv};
        acc[f][1] = acc[f][0];
    }
    #pragma unroll
    for (int ks = 0; ks < 8; ks++) {
        short8v ah0 = *reinterpret_cast<const short8v*>(&inh[swz(lm, ks * 32 + lq * 8, 256)]);
        short8v al0 = *reinterpret_cast<const short8v*>(&inl[swz(lm, ks * 32 + lq * 8, 256)]);
        short8v ah1 = *reinterpret_cast<const short8v*>(&inh[swz(16 + lm, ks * 32 + lq * 8, 256)]);
        short8v al1 = *reinterpret_cast<const short8v*>(&inl[swz(16 + lm, ks * 32 + lq * 8, 256)]);
        #pragma unroll
        for (int f = 0; f < 2; f++) {
            size_t bi = ((size_t)((2 * w + f) * 8 + ks) * 64 + lane) * 8;
            short8v bh = *reinterpret_cast<const short8v*>(wh + bi);
            short8v bl = *reinterpret_cast<const short8v*>(wl + bi);
            acc[f][0] = MFMA16(ah0, bh, acc[f][0]);
            acc[f][0] = MFMA16(al0, bh, acc[f][0]);
            acc[f][0] = MFMA16(ah0, bl, acc[f][0]);
            acc[f][1] = MFMA16(ah1, bh, acc[f][1]);
            acc[f][1] = MFMA16(al1, bh, acc[f][1]);
            acc[f][1] = MFMA16(ah1, bl, acc[f][1]);
        }
    }
    #pragma unroll
    for (int f = 0; f < 2; f++)
        #pragma unroll
        for (int m = 0; m < 2; m++) {
            if (tf32) {
                #pragma unroll
                for (int r = 0; r < 4; r++) {
                    float v = acc[f][m][r];
                    if (do_relu) v = fmaxf(v, 0.f);
                    tf32[(m * 16 + lq * 4 + r) * 256 + (2 * w + f) * 16 + lm] = v;
                }
            } else {
                float v0 = acc[f][m][0], v1 = acc[f][m][1], v2 = acc[f][m][2], v3 = acc[f][m][3];
                if (do_relu) {
                    v0 = fmaxf(v0, 0.f); v1 = fmaxf(v1, 0.f);
                    v2 = fmaxf(v2, 0.f); v3 = fmaxf(v3, 0.f);
                }
                store_quad(oth, otl, v0, v1, v2, v3,
                           m * 16 + lq * 4, (2 * w + f) * 16 + lm, 256);
            }
        }
}

// ---------------- fused MFMA tail: pooled->attn->t->LN->out -----------------
__global__ __launch_bounds__(512, 4) void tail_mfma_kernel(
    const float* __restrict__ hw,
    const unsigned short* __restrict__ Gh, const unsigned short* __restrict__ Gl,
    const float* __restrict__ Gd,
    const unsigned short* __restrict__ Woh, const unsigned short* __restrict__ Wol,
    const float* __restrict__ b_out,
    const unsigned short* __restrict__ Wh1h, const unsigned short* __restrict__ Wh1l,
    const float* __restrict__ bh1,
    const float* __restrict__ ln_g, const float* __restrict__ ln_b,
    const unsigned short* __restrict__ Wh2h, const unsigned short* __restrict__ Wh2l,
    const float* __restrict__ bh2,
    float* __restrict__ out)
{
    __shared__ __attribute__((aligned(16))) unsigned short L[32768];
    unsigned short* Ah = L;
    unsigned short* Al = L + 8192;
    unsigned short* Bh = L + 16384;
    unsigned short* Bl = L + 24576;
    float* tf = reinterpret_cast<float*>(L + 16384);
    const int tid = threadIdx.x;
    const int lane = tid & 63, w = tid >> 6;
    const int lm = lane & 15, lq = lane >> 4;
    const int g0 = blockIdx.x * 32;

    {   // load hw tile [32x256] -> A hi/lo swizzled
        const float4* hp = reinterpret_cast<const float4*>(hw + (size_t)g0 * 256);
        #pragma unroll
        for (int i = 0; i < 4; i++) {
            int e = tid + 512 * i;
            int row = e >> 6, c0 = (e & 63) * 4;
            float4 u = hp[e];
            unsigned int p01 = cvtpk(u.x, u.y);
            unsigned int p23 = cvtpk(u.z, u.w);
            float h0 = __uint_as_float(p01 << 16), h1 = __uint_as_float(p01 & 0xffff0000u);
            float h2 = __uint_as_float(p23 << 16), h3 = __uint_as_float(p23 & 0xffff0000u);
            unsigned int q01 = cvtpk(u.x - h0, u.y - h1);
            unsigned int q23 = cvtpk(u.z - h2, u.w - h3);
            int idx = swz(row, c0, 256);
            *reinterpret_cast<uint2*>(&Ah[idx]) = make_uint2(p01, p23);
            *reinterpret_cast<uint2*>(&Al[idx]) = make_uint2(q01, q23);
        }
    }
    __syncthreads();
    tail_stage(Ah, Al, Gh, Gl, Gd, false, Bh, Bl, nullptr, w, lane, lm, lq);
    __syncthreads();
    tail_stage(Bh, Bl, Woh, Wol, b_out, true, Ah, Al, nullptr, w, lane, lm, lq);
    __syncthreads();
    tail_stage(Ah, Al, Wh1h, Wh1l, bh1, true, nullptr, nullptr, tf, w, lane, lm, lq);
    __syncthreads();
    {   // LN per row (16 threads per row), write normalized bf16 hi/lo -> A
        const int row = tid >> 4, l16 = tid & 15;
        float s = 0.f;
        #pragma unroll
        for (int k = 0; k < 16; k++) s += tf[row * 256 + l16 + 16 * k];
        #pragma unroll
        for (int m = 1; m < 16; m <<= 1) s += __shfl_xor(s, m, 16);
        float mu = s * (1.f / 256.f);
        float v = 0.f;
        #pragma unroll
        for (int k = 0; k < 16; k++) {
            float d = tf[row * 256 + l16 + 16 * k] - mu;
            v += d * d;
        }
        #pragma unroll
        for (int m = 1; m < 16; m <<= 1) v += __shfl_xor(v, m, 16);
        float rs = rsqrtf(v * (1.f / 256.f) + 1e-5f);
        #pragma unroll
        for (int k = 0; k < 16; k++) {
            int col = l16 + 16 * k;
            float val = (tf[row * 256 + col] - mu) * rs * ln_g[col] + ln_b[col];
            unsigned short hi = f2bf(val);
            int idx = swz(row, col, 256);
            Ah[idx] = hi;
            Al[idx] = f2bf(val - bf2f(hi));
        }
    }
    __syncthreads();
    {   // S: out = t @ Wh2 + bh2   [32x256]@[256x1024]
        f32x4 acc[8][2];
        #pragma unroll
        for (int f = 0; f < 8; f++) {
            float bv = bh2[(8 * w + f) * 16 + lm];
            acc[f][0] = f32x4{bv, bv, bv, bv};
            acc[f][1] = acc[f][0];
        }
        #pragma unroll
        for (int ks = 0; ks < 8; ks++) {
            short8v ah0 = *reinterpret_cast<const short8v*>(&Ah[swz(lm, ks * 32 + lq * 8, 256)]);
            short8v al0 = *reinterpret_cast<const short8v*>(&Al[swz(lm, ks * 32 + lq * 8, 256)]);
            short8v ah1 = *reinterpret_cast<const short8v*>(&Ah[swz(16 + lm, ks * 32 + lq * 8, 256)]);
            short8v al1 = *reinterpret_cast<const short8v*>(&Al[swz(16 + lm, ks * 32 + lq * 8, 256)]);
            #pragma unroll
            for (int f = 0; f < 8; f++) {
                size_t bi = ((size_t)((8 * w + f) * 8 + ks) * 64 + lane) * 8;
                short8v bh = *reinterpret_cast<const short8v*>(Wh2h + bi);
                short8v bl = *reinterpret_cast<const short8v*>(Wh2l + bi);
                acc[f][0] = MFMA16(ah0, bh, acc[f][0]);
                acc[f][0] = MFMA16(al0, bh, acc[f][0]);
                acc[f][0] = MFMA16(ah0, bl, acc[f][0]);
                acc[f][1] = MFMA16(ah1, bh, acc[f][1]);
                acc[f][1] = MFMA16(al1, bh, acc[f][1]);
                acc[f][1] = MFMA16(ah1, bl, acc[f][1]);
            }
        }
        #pragma unroll
        for (int f = 0; f < 8; f++)
            #pragma unroll
            for (int m = 0; m < 2; m++)
                #pragma unroll
                for (int r = 0; r < 4; r++)
                    out[(size_t)(g0 + m * 16 + lq * 4 + r) * 1024 + (8 * w + f) * 16 + lm]
                        = acc[f][m][r];
    }
}

extern "C" void kernel_launch(void* const* d_in, const int* in_sizes, int n_in,
                              void* d_out, int out_size, void* d_ws, size_t ws_size,
                              hipStream_t stream) {
    const float* x       = (const float*)d_in[0];
    const int*   edge    = (const int*)d_in[1];
    const float* W_embed = (const float*)d_in[3];
    const float* b_embed = (const float*)d_in[4];
    const float* W1 = (const float*)d_in[5];
    const float* b1 = (const float*)d_in[6];
    const float* W2 = (const float*)d_in[7];
    const float* b2 = (const float*)d_in[8];
    const float* W3 = (const float*)d_in[9];
    const float* b3 = (const float*)d_in[10];
    const float* Wp = (const float*)d_in[11];
    const float* bp = (const float*)d_in[12];
    const float* q  = (const float*)d_in[13];
    const float* W_in  = (const float*)d_in[14];
    const float* b_in  = (const float*)d_in[15];
    const float* W_out = (const float*)d_in[16];
    const float* b_out = (const float*)d_in[17];
    const float* Wh1 = (const float*)d_in[18];
    const float* bh1 = (const float*)d_in[19];
    const float* ln_g = (const float*)d_in[20];
    const float* ln_b = (const float*)d_in[21];
    const float* Wh2 = (const float*)d_in[22];
    const float* bh2 = (const float*)d_in[23];
    float* out = (float*)d_out;

    char* ws = (char*)d_ws;
    int*   cnt  = (int*)(ws + 0);
    float* h    = (float*)(ws + 393216);
    float* hw   = (float*)(ws + 25559040);
    float* prec = (float*)(ws + 27656192);
    unsigned short* W1h = (unsigned short*)(ws + 27657232);
    unsigned short* W1l = (unsigned short*)(ws + 27853840);
    unsigned short* W2h = (unsigned short*)(ws + 28050448);
    unsigned short* W2l = (unsigned short*)(ws + 29623312);
    unsigned short* W3h = (unsigned short*)(ws + 31196176);
    unsigned short* W3l = (unsigned short*)(ws + 31589392);
    unsigned short* Weh = (unsigned short*)(ws + 31982608);
    unsigned short* Wel = (unsigned short*)(ws + 31998992);
    float* Gm  = (float*)(ws + 32015376);
    float* Gd  = (float*)(ws + 32277520);
    unsigned short* Gfh  = (unsigned short*)(ws + 32278544);
    unsigned short* Gfl  = (unsigned short*)(ws + 32409616);
    unsigned short* Wofh = (unsigned short*)(ws + 32540688);
    unsigned short* Wofl = (unsigned short*)(ws + 32671760);
    unsigned short* Wh1fh= (unsigned short*)(ws + 32802832);
    unsigned short* Wh1fl= (unsigned short*)(ws + 32933904);
    unsigned short* Wh2fh= (unsigned short*)(ws + 33064976);
    unsigned short* Wh2fl= (unsigned short*)(ws + 33589264);

    zero_cnt_kernel<<<N_NODES / 256, 256, 0, stream>>>(cnt);
    hist_kernel<<<N_EDGES / 256, 256, 0, stream>>>(edge, cnt);

    prep_frag_kernel<<<1 * (64 / 16) * (128 / 32), 64, 0, stream>>>(W_embed, Weh, Wel, 128, 64);
    prep_frag_kernel<<<6 * (256 / 16) * (64 / 32), 64, 0, stream>>>(W1, W1h, W1l, 64, 256);
    prep_frag_kernel<<<6 * (512 / 16) * (256 / 32), 64, 0, stream>>>(W2, W2h, W2l, 256, 512);
    prep_frag_kernel<<<6 * (64 / 16) * (512 / 32), 64, 0, stream>>>(W3, W3h, W3l, 512, 64);

    gbuild_kernel<<<256, 256, 0, stream>>>(Wp, bp, W_in, b_in, Gm, Gd);
    prep_frag_kernel<<<(256 / 16) * (256 / 32), 64, 0, stream>>>(Gm, Gfh, Gfl, 256, 256);
    prep_frag_kernel<<<(256 / 16) * (256 / 32), 64, 0, stream>>>(W_out, Wofh, Wofl, 256, 256);
    prep_frag_kernel<<<(256 / 16) * (256 / 32), 64, 0, stream>>>(Wh1, Wh1fh, Wh1fl, 256, 256);
    prep_frag_kernel<<<(1024 / 16) * (256 / 32), 64, 0, stream>>>(Wh2, Wh2fh, Wh2fl, 256, 1024);

    embed_mfma_kernel<<<N_NODES / 32, 256, 0, stream>>>(x, Weh, Wel, b_embed, h);
    for (int l = 0; l < N_LAYERS_; l++) {
        layer_mfma_kernel<<<N_NODES / 32, 512, 0, stream>>>(
            h, cnt,
            W1h + (size_t)l * EMB * HID,     W1l + (size_t)l * EMB * HID,     b1 + (size_t)l * HID,
            W2h + (size_t)l * HID * 2 * HID, W2l + (size_t)l * HID * 2 * HID, b2 + (size_t)l * 2 * HID,
            W3h + (size_t)l * 2 * HID * EMB, W3l + (size_t)l * 2 * HID * EMB, b3 + (size_t)l * EMB);
    }
    prec_kernel<<<1, 256, 0, stream>>>(q, W_in, b_in, Wp, bp, prec);
    attnpool_kernel<<<N_GRAPHS, 64, 0, stream>>>(h, prec, hw);
    tail_mfma_kernel<<<N_GRAPHS / 32, 512, 0, stream>>>(
        hw, Gfh, Gfl, Gd, Wofh, Wofl, b_out, Wh1fh, Wh1fl, bh1,
        ln_g, ln_b, Wh2fh, Wh2fl, bh2, out);
}